// Round 5
// baseline (6639.483 us; speedup 1.0000x reference)
//
#include <hip/hip_runtime.h>
#include <hip/hip_bf16.h>
#include <math.h>

typedef __attribute__((ext_vector_type(8))) short bf16x8;
typedef __attribute__((ext_vector_type(4))) float f32x4;
typedef __attribute__((ext_vector_type(4))) unsigned short u16x4;

#define B_   16
#define C_   128
#define CHW_ 131072   // 128*32*32
#define K_   1152     // 128*9
#define NBLK 256      // persistent grid: 16 b x 16 rowpairs, 1 block/CU

__device__ __forceinline__ unsigned short f2bf(float f) {
  union { float f; unsigned int i; } v; v.f = f;
  unsigned int lsb = (v.i >> 16) & 1u;
  v.i += 0x7fffu + lsb;
  return (unsigned short)(v.i >> 16);
}

// ---- weight prep: W[O][I][3][3] f32 -> wpk[ks][co][ci&31] bf16, ks = off*4 + (ci>>5)
__global__ void prep_weights(const float* __restrict__ W1, const float* __restrict__ W2,
                             unsigned short* __restrict__ w1bf, unsigned short* __restrict__ w2bf) {
  int j = blockIdx.x * 256 + threadIdx.x;
  if (j >= 2 * 147456) return;
  int which = j / 147456;
  int r = j - which * 147456;
  int ks = r >> 12;
  int co = (r >> 5) & 127;
  int c5 = r & 31;
  int off = ks >> 2;
  int ci  = (ks & 3) * 32 + c5;
  const float* src = which ? W2 : W1;
  unsigned short* dst = which ? w2bf : w1bf;
  dst[r] = f2bf(src[(co * 128 + ci) * 9 + off]);
}

// ---- init: y32 = y0 (NCHW f32); dout[:,t=0,...] = y0
__global__ void init_copy(const float* __restrict__ y0, float* __restrict__ y32,
                          float* __restrict__ dout) {
  int i = blockIdx.x * 256 + threadIdx.x;
  if (i >= B_ * CHW_) return;
  float v = y0[i];
  y32[i] = v;
  int b = i >> 17, chw = i & (CHW_ - 1);
  dout[b * 25 * CHW_ + chw] = v;
}

// ---- init: tmp_bf (NHWC bf16) = transpose(y0)
__global__ void init_transpose(const float* __restrict__ y0, unsigned short* __restrict__ tmp_bf) {
  __shared__ float t[32][33];
  int blk = blockIdx.x;          // 16 b * 4 co-tiles * 32 pix-tiles = 2048
  int b = blk >> 7;
  int rem = blk & 127;
  int co0 = (rem >> 5) * 32;
  int p0  = (rem & 31) * 32;
  int tx = threadIdx.x & 31, ty = threadIdx.x >> 5;
  #pragma unroll
  for (int k = 0; k < 4; k++) {
    int cl = ty + k * 8;
    t[cl][tx] = y0[b * CHW_ + (co0 + cl) * 1024 + p0 + tx];
  }
  __syncthreads();
  #pragma unroll
  for (int k = 0; k < 4; k++) {
    int pl = ty + k * 8;
    tmp_bf[(b * 1024 + p0 + pl) * 128 + co0 + tx] = f2bf(t[tx][pl]);
  }
}

// ---- device-scope sense-reversing grid barrier.
// cnt at bar[0], gen at bar[32] (separate 128B lines). State zeroed by
// hipMemsetAsync before each launch -> deterministic across graph replays.
__device__ __forceinline__ void gbar(unsigned* bar) {
  __syncthreads();
  if (threadIdx.x == 0) {
    __threadfence();   // release: drain stores, write back dirty L2 (cross-XCD)
    unsigned* cnt = bar;
    unsigned* gen = bar + 32;
    unsigned g = __hip_atomic_load(gen, __ATOMIC_RELAXED, __HIP_MEMORY_SCOPE_AGENT);
    unsigned a = __hip_atomic_fetch_add(cnt, 1u, __ATOMIC_ACQ_REL, __HIP_MEMORY_SCOPE_AGENT);
    if (a == NBLK - 1) {
      __hip_atomic_store(cnt, 0u, __ATOMIC_RELAXED, __HIP_MEMORY_SCOPE_AGENT);
      __hip_atomic_fetch_add(gen, 1u, __ATOMIC_RELEASE, __HIP_MEMORY_SCOPE_AGENT);
    } else {
      int guard = 0;
      while (__hip_atomic_load(gen, __ATOMIC_RELAXED, __HIP_MEMORY_SCOPE_AGENT) == g) {
        __builtin_amdgcn_s_sleep(4);
        if (++guard > 4000000) break;   // anti-hang: fail loudly, never deadlock
      }
    }
    __threadfence();   // acquire: invalidate L1/L2 so we see producers' data
  }
  __syncthreads();
}

// ---- persistent fused ODE solver: 24 RK4 steps x 8 conv phases, one launch.
// Block: 2 output rows x 128 co, 8 waves. Wave: 32co x 32sp (1 row).
// Per K-step: 2 A-frag L2 loads + 2 B-frag LDS reads -> 4 MFMA.
// ph even: z = tanh(conv(tmp,W1)+b1);  ph odd: stage N=(ph>>1)+1 RK4 update.
__global__ __launch_bounds__(512, 2)
void ode_persistent(const unsigned short* __restrict__ w1bf,
                    const unsigned short* __restrict__ w2bf,
                    const float* __restrict__ b1v, const float* __restrict__ b2v,
                    unsigned short* __restrict__ tmp_bf, unsigned short* __restrict__ z_bf,
                    float* __restrict__ y32, float* __restrict__ acc32,
                    float* __restrict__ dout, const float* __restrict__ tarr,
                    unsigned* __restrict__ bar)
{
  // input tile: 4 rows (r0-1..r0+2) x 34 cols (-1..32) x 128 ci, row stride 136
  __shared__ unsigned short tile[136 * 136];
  const int tid  = threadIdx.x;
  const int b    = blockIdx.x >> 4;
  const int r0   = (blockIdx.x & 15) * 2;
  const int lane = tid & 63;
  const int wave = tid >> 6;
  const int lhi  = lane >> 4;         // 0..3 (K octet / D row group)
  const int llo  = lane & 15;         // A: co row, B: sp col, D: col
  const int row_w = wave & 1;         // which of the 2 output rows
  const int co_w  = (wave >> 1) * 32; // 32-co band per wave

  for (int step = 0; step < 24; ++step) {
    float t0 = tarr[step];
    float t1 = tarr[step + 1];
    // keep one operand in a VGPR: avoids V_ADD_F32 with two SGPR sources
    // (constant-bus violation -> backend compile error on gfx950)
    asm volatile("" : "+v"(t1));
    const float dt = t1 - t0;
    const float dt6 = dt * (1.f / 6.f), dt3 = dt * (1.f / 3.f), dth = dt * 0.5f;

    for (int ph = 0; ph < 8; ++ph) {
      const bool c1 = !(ph & 1);
      const unsigned short* in_bf = c1 ? tmp_bf : z_bf;
      const unsigned short* wpk   = c1 ? w1bf : w2bf;
      const float* bias           = c1 ? b1v : b2v;
      unsigned short* out_bf      = c1 ? z_bf : tmp_bf;
      const int stage             = c1 ? 0 : ((ph >> 1) + 1);

      // stage input tile (zero-padded halo), 16B chunks, coalesced
      for (int chunk = tid; chunk < 136 * 16; chunk += 512) {
        int pix = chunk >> 4;
        int oct = chunk & 15;
        int tr = pix / 34, tc = pix - tr * 34;
        int gr = r0 - 1 + tr, gc = tc - 1;
        bf16x8 v = {0, 0, 0, 0, 0, 0, 0, 0};
        if ((unsigned)gr < 32u && (unsigned)gc < 32u)
          v = *(const bf16x8*)(in_bf + ((b * 32 + gr) * 32 + gc) * 128 + oct * 8);
        *(bf16x8*)(tile + pix * 136 + oct * 8) = v;
      }
      __syncthreads();

      f32x4 acc[2][2];
      #pragma unroll
      for (int i = 0; i < 2; i++)
        #pragma unroll
        for (int j = 0; j < 2; j++)
          acc[i][j] = (f32x4){0.f, 0.f, 0.f, 0.f};

      const unsigned short* abase = wpk + (co_w + llo) * 32 + lhi * 8;

      for (int off = 0; off < 9; ++off) {
        const int dh = off / 3;
        const int dw = off - 3 * dh;
        const int pixb = (dh + row_w) * 34 + llo + dw;
        #pragma unroll
        for (int kk = 0; kk < 4; ++kk) {
          const int ks = off * 4 + kk;
          bf16x8 afr[2], bfr[2];
          afr[0] = *(const bf16x8*)(abase + ks * 4096);
          afr[1] = *(const bf16x8*)(abase + ks * 4096 + 512);
          bfr[0] = *(const bf16x8*)(tile + pixb * 136 + kk * 32 + lhi * 8);
          bfr[1] = *(const bf16x8*)(tile + (pixb + 16) * 136 + kk * 32 + lhi * 8);
          #pragma unroll
          for (int ct = 0; ct < 2; ++ct)
            #pragma unroll
            for (int spt = 0; spt < 2; ++spt)
              acc[ct][spt] = __builtin_amdgcn_mfma_f32_16x16x32_bf16(afr[ct], bfr[spt], acc[ct][spt], 0, 0, 0);
        }
      }

      const int row = r0 + row_w;
      #pragma unroll
      for (int ct = 0; ct < 2; ++ct) {
        const int co0 = co_w + ct * 16 + lhi * 4;
        #pragma unroll
        for (int spt = 0; spt < 2; ++spt) {
          const int col = spt * 16 + llo;
          const int pnhwc = (b * 1024 + row * 32 + col) * 128 + co0;
          f32x4 a = acc[ct][spt];
          u16x4 pk;
          if (stage == 0) {
            #pragma unroll
            for (int reg = 0; reg < 4; ++reg) {
              float v = tanhf(a[reg] + bias[co0 + reg]);
              pk[reg] = f2bf(v);
            }
            *(u16x4*)(out_bf + pnhwc) = pk;
          } else {
            const int idx0 = b * CHW_ + co0 * 1024 + row * 32 + col;
            #pragma unroll
            for (int reg = 0; reg < 4; ++reg) {
              float kv = a[reg] + bias[co0 + reg];
              int id = idx0 + reg * 1024;
              float tv;
              if (stage == 1)      { float yv = y32[id]; acc32[id] = yv + dt6 * kv; tv = yv + dth * kv; }
              else if (stage == 2) { float yv = y32[id]; acc32[id] += dt3 * kv;     tv = yv + dth * kv; }
              else if (stage == 3) { float yv = y32[id]; acc32[id] += dt3 * kv;     tv = yv + dt * kv; }
              else {
                tv = acc32[id] + dt6 * kv;
                y32[id] = tv;
                dout[(b * 25 + step + 1) * CHW_ + co0 * 1024 + row * 32 + col + reg * 1024] = tv;
              }
              pk[reg] = f2bf(tv);
            }
            *(u16x4*)(out_bf + pnhwc) = pk;
          }
        }
      }

      gbar(bar);
    }
  }
}

extern "C" void kernel_launch(void* const* d_in, const int* in_sizes, int n_in,
                              void* d_out, int out_size, void* d_ws, size_t ws_size,
                              hipStream_t stream) {
  const float* y0   = (const float*)d_in[0];
  const float* tarr = (const float*)d_in[1];
  const float* W1   = (const float*)d_in[2];
  const float* b1   = (const float*)d_in[3];
  const float* W2   = (const float*)d_in[4];
  const float* b2   = (const float*)d_in[5];
  float* dout = (float*)d_out;

  char* ws = (char*)d_ws;
  float* y32             = (float*)(ws);                          // 8 MB
  float* acc32           = (float*)(ws + (8u << 20));             // 8 MB
  unsigned short* tmp_bf = (unsigned short*)(ws + (16u << 20));   // 4 MB (NHWC)
  unsigned short* z_bf   = (unsigned short*)(ws + (20u << 20));   // 4 MB (NHWC)
  unsigned short* w1bf   = (unsigned short*)(ws + (24u << 20));   // 288 KB
  unsigned short* w2bf   = (unsigned short*)(ws + (24u << 20) + 294912);
  unsigned* bar          = (unsigned*)(ws + (24u << 20) + 655360);

  prep_weights<<<(2 * 147456 + 255) / 256, 256, 0, stream>>>(W1, W2, w1bf, w2bf);
  init_copy<<<(B_ * CHW_ + 255) / 256, 256, 0, stream>>>(y0, y32, dout);
  init_transpose<<<2048, 256, 0, stream>>>(y0, tmp_bf);
  hipMemsetAsync(bar, 0, 256, stream);

  unsigned short* w1p = w1bf; unsigned short* w2p = w2bf;
  const float* b1p = b1; const float* b2p = b2;
  unsigned short* tp = tmp_bf; unsigned short* zp = z_bf;
  float* yp = y32; float* ap = acc32; float* dp = dout;
  const float* tap = tarr; unsigned* bp = bar;
  void* kargs[] = {&w1p, &w2p, &b1p, &b2p, &tp, &zp, &yp, &ap, &dp, &tap, &bp};
  hipError_t rc = hipLaunchCooperativeKernel((void*)ode_persistent, dim3(NBLK), dim3(512),
                                             kargs, 0, stream);
  if (rc != hipSuccess) {
    // fallback: plain launch. 1 block/CU (LDS 37KB, VGPR<=256) -> co-resident.
    ode_persistent<<<NBLK, 512, 0, stream>>>(w1p, w2p, b1p, b2p, tp, zp, yp, ap, dp, tap, bp);
  }
}

// Round 6
// 3741.866 us; speedup vs baseline: 1.7744x; 1.7744x over previous
//
#include <hip/hip_runtime.h>
#include <hip/hip_bf16.h>
#include <math.h>

typedef __attribute__((ext_vector_type(8))) short bf16x8;
typedef __attribute__((ext_vector_type(4))) float f32x4;
typedef __attribute__((ext_vector_type(4))) unsigned short u16x4;

#define B_   16
#define C_   128
#define CHW_ 131072   // 128*32*32
#define NBLK 256      // persistent grid: 16 b x 16 rowpairs, 1 block/CU

__device__ __forceinline__ unsigned short f2bf(float f) {
  union { float f; unsigned int i; } v; v.f = f;
  unsigned int lsb = (v.i >> 16) & 1u;
  v.i += 0x7fffu + lsb;
  return (unsigned short)(v.i >> 16);
}

// ---- weight prep: W[O][I][3][3] f32 -> wpk[ks][co][ci&31] bf16, ks = off*4 + (ci>>5)
__global__ void prep_weights(const float* __restrict__ W1, const float* __restrict__ W2,
                             unsigned short* __restrict__ w1bf, unsigned short* __restrict__ w2bf) {
  int j = blockIdx.x * 256 + threadIdx.x;
  if (j >= 2 * 147456) return;
  int which = j / 147456;
  int r = j - which * 147456;
  int ks = r >> 12;
  int co = (r >> 5) & 127;
  int c5 = r & 31;
  int off = ks >> 2;
  int ci  = (ks & 3) * 32 + c5;
  const float* src = which ? W2 : W1;
  unsigned short* dst = which ? w2bf : w1bf;
  dst[r] = f2bf(src[(co * 128 + ci) * 9 + off]);
}

// ---- init: y32 = y0 (NCHW f32); dout[:,t=0,...] = y0
__global__ void init_copy(const float* __restrict__ y0, float* __restrict__ y32,
                          float* __restrict__ dout) {
  int i = blockIdx.x * 256 + threadIdx.x;
  if (i >= B_ * CHW_) return;
  float v = y0[i];
  y32[i] = v;
  int b = i >> 17, chw = i & (CHW_ - 1);
  dout[b * 25 * CHW_ + chw] = v;
}

// ---- init: tmp_bf (NHWC bf16) = transpose(y0)
__global__ void init_transpose(const float* __restrict__ y0, unsigned short* __restrict__ tmp_bf) {
  __shared__ float t[32][33];
  int blk = blockIdx.x;          // 16 b * 4 co-tiles * 32 pix-tiles = 2048
  int b = blk >> 7;
  int rem = blk & 127;
  int co0 = (rem >> 5) * 32;
  int p0  = (rem & 31) * 32;
  int tx = threadIdx.x & 31, ty = threadIdx.x >> 5;
  #pragma unroll
  for (int k = 0; k < 4; k++) {
    int cl = ty + k * 8;
    t[cl][tx] = y0[b * CHW_ + (co0 + cl) * 1024 + p0 + tx];
  }
  __syncthreads();
  #pragma unroll
  for (int k = 0; k < 4; k++) {
    int pl = ty + k * 8;
    tmp_bf[(b * 1024 + p0 + pl) * 128 + co0 + tx] = f2bf(t[tx][pl]);
  }
}

// ---- per-image barrier: 16 blocks, monotone arrival counter (no reset -> no
// reuse race under relaxed atomics). No device fences anywhere: tmp/z data
// moves via agent-scope atomics (device-coherent through LLC), so L2-cached
// weights / y32 / acc32 are never invalidated.
__device__ __forceinline__ void gbar_img(unsigned* cnt, unsigned target) {
  asm volatile("s_waitcnt vmcnt(0)" ::: "memory");   // each wave drains its stores
  __syncthreads();
  if (threadIdx.x == 0) {
    __hip_atomic_fetch_add(cnt, 1u, __ATOMIC_RELAXED, __HIP_MEMORY_SCOPE_AGENT);
    int guard = 0;
    while (__hip_atomic_load(cnt, __ATOMIC_RELAXED, __HIP_MEMORY_SCOPE_AGENT) < target) {
      __builtin_amdgcn_s_sleep(2);
      if (++guard > 100000000) break;   // fail loudly, never hang
    }
  }
  __syncthreads();
  asm volatile("" ::: "memory");
}

__device__ __forceinline__ bf16x8 ld_coherent16(const unsigned short* p) {
  union { unsigned long long u[2]; bf16x8 v; } r;
  const unsigned long long* q = (const unsigned long long*)p;
  r.u[0] = __hip_atomic_load(q,     __ATOMIC_RELAXED, __HIP_MEMORY_SCOPE_AGENT);
  r.u[1] = __hip_atomic_load(q + 1, __ATOMIC_RELAXED, __HIP_MEMORY_SCOPE_AGENT);
  return r.v;
}

__device__ __forceinline__ void st_coherent8(unsigned short* p, u16x4 v) {
  union { u16x4 v; unsigned long long u; } r; r.v = v;
  __hip_atomic_store((unsigned long long*)p, r.u, __ATOMIC_RELAXED, __HIP_MEMORY_SCOPE_AGENT);
}

// ---- persistent fused ODE solver: 24 RK4 steps x 8 conv phases, one launch.
// Block: 2 output rows x 128 co, 8 waves. Wave: 32co x 32sp (1 row).
// Per K-step: 2 A-frag L2 loads + 2 B-frag LDS reads -> 4 MFMA.
// ph even: z = tanh(conv(tmp,W1)+b1);  ph odd: stage N=(ph>>1)+1 RK4 update.
__global__ __launch_bounds__(512, 2)
void ode_persistent(const unsigned short* __restrict__ w1bf,
                    const unsigned short* __restrict__ w2bf,
                    const float* __restrict__ b1v, const float* __restrict__ b2v,
                    unsigned short* __restrict__ tmp_bf, unsigned short* __restrict__ z_bf,
                    float* __restrict__ y32, float* __restrict__ acc32,
                    float* __restrict__ dout, const float* __restrict__ tarr,
                    unsigned* __restrict__ bar)
{
  // input tile: 4 rows (r0-1..r0+2) x 34 cols (-1..32) x 128 ci, row stride 136
  __shared__ unsigned short tile[136 * 136];
  const int tid  = threadIdx.x;
  const int b    = blockIdx.x >> 4;
  const int r0   = (blockIdx.x & 15) * 2;
  const int lane = tid & 63;
  const int wave = tid >> 6;
  const int lhi  = lane >> 4;         // 0..3 (K octet / D row group)
  const int llo  = lane & 15;         // A: co row, B: sp col, D: col
  const int row_w = wave & 1;         // which of the 2 output rows
  const int co_w  = (wave >> 1) * 32; // 32-co band per wave

  unsigned* const mycnt = bar + b * 64;   // per-image barrier line (256B apart)
  unsigned phase_no = 0;

  for (int step = 0; step < 24; ++step) {
    float t0 = tarr[step];
    float t1 = tarr[step + 1];
    // keep one operand in a VGPR: avoids V_ADD_F32 with two SGPR sources
    // (constant-bus violation -> backend compile error on gfx950)
    asm volatile("" : "+v"(t1));
    const float dt = t1 - t0;
    const float dt6 = dt * (1.f / 6.f), dt3 = dt * (1.f / 3.f), dth = dt * 0.5f;

    for (int ph = 0; ph < 8; ++ph) {
      const bool c1 = !(ph & 1);
      const unsigned short* in_bf = c1 ? tmp_bf : z_bf;
      const unsigned short* wpk   = c1 ? w1bf : w2bf;
      const float* bias           = c1 ? b1v : b2v;
      unsigned short* out_bf      = c1 ? z_bf : tmp_bf;
      const int stage             = c1 ? 0 : ((ph >> 1) + 1);

      // stage input tile (zero-padded halo); device-coherent 2x8B loads
      for (int chunk = tid; chunk < 136 * 16; chunk += 512) {
        int pix = chunk >> 4;
        int oct = chunk & 15;
        int tr = pix / 34, tc = pix - tr * 34;
        int gr = r0 - 1 + tr, gc = tc - 1;
        bf16x8 v = {0, 0, 0, 0, 0, 0, 0, 0};
        if ((unsigned)gr < 32u && (unsigned)gc < 32u)
          v = ld_coherent16(in_bf + ((b * 32 + gr) * 32 + gc) * 128 + oct * 8);
        *(bf16x8*)(tile + pix * 136 + oct * 8) = v;
      }
      __syncthreads();

      f32x4 acc[2][2];
      #pragma unroll
      for (int i = 0; i < 2; i++)
        #pragma unroll
        for (int j = 0; j < 2; j++)
          acc[i][j] = (f32x4){0.f, 0.f, 0.f, 0.f};

      const unsigned short* abase = wpk + (co_w + llo) * 32 + lhi * 8;

      for (int off = 0; off < 9; ++off) {
        const int dh = off / 3;
        const int dw = off - 3 * dh;
        const int pixb = (dh + row_w) * 34 + llo + dw;
        #pragma unroll
        for (int kk = 0; kk < 4; ++kk) {
          const int ks = off * 4 + kk;
          bf16x8 afr[2], bfr[2];
          afr[0] = *(const bf16x8*)(abase + ks * 4096);
          afr[1] = *(const bf16x8*)(abase + ks * 4096 + 512);
          bfr[0] = *(const bf16x8*)(tile + pixb * 136 + kk * 32 + lhi * 8);
          bfr[1] = *(const bf16x8*)(tile + (pixb + 16) * 136 + kk * 32 + lhi * 8);
          #pragma unroll
          for (int ct = 0; ct < 2; ++ct)
            #pragma unroll
            for (int spt = 0; spt < 2; ++spt)
              acc[ct][spt] = __builtin_amdgcn_mfma_f32_16x16x32_bf16(afr[ct], bfr[spt], acc[ct][spt], 0, 0, 0);
        }
      }

      const int row = r0 + row_w;
      #pragma unroll
      for (int ct = 0; ct < 2; ++ct) {
        const int co0 = co_w + ct * 16 + lhi * 4;
        #pragma unroll
        for (int spt = 0; spt < 2; ++spt) {
          const int col = spt * 16 + llo;
          const int pnhwc = (b * 1024 + row * 32 + col) * 128 + co0;
          f32x4 a = acc[ct][spt];
          u16x4 pk;
          if (stage == 0) {
            #pragma unroll
            for (int reg = 0; reg < 4; ++reg) {
              float v = tanhf(a[reg] + bias[co0 + reg]);
              pk[reg] = f2bf(v);
            }
            st_coherent8(out_bf + pnhwc, pk);
          } else {
            const int idx0 = b * CHW_ + co0 * 1024 + row * 32 + col;
            #pragma unroll
            for (int reg = 0; reg < 4; ++reg) {
              float kv = a[reg] + bias[co0 + reg];
              int id = idx0 + reg * 1024;
              float tv;
              if (stage == 1)      { float yv = y32[id]; acc32[id] = yv + dt6 * kv; tv = yv + dth * kv; }
              else if (stage == 2) { float yv = y32[id]; acc32[id] += dt3 * kv;     tv = yv + dth * kv; }
              else if (stage == 3) { float yv = y32[id]; acc32[id] += dt3 * kv;     tv = yv + dt * kv; }
              else {
                tv = acc32[id] + dt6 * kv;
                y32[id] = tv;
                dout[(b * 25 + step + 1) * CHW_ + co0 * 1024 + row * 32 + col + reg * 1024] = tv;
              }
              pk[reg] = f2bf(tv);
            }
            st_coherent8(out_bf + pnhwc, pk);
          }
        }
      }

      ++phase_no;
      gbar_img(mycnt, phase_no * 16u);
    }
  }
}

extern "C" void kernel_launch(void* const* d_in, const int* in_sizes, int n_in,
                              void* d_out, int out_size, void* d_ws, size_t ws_size,
                              hipStream_t stream) {
  const float* y0   = (const float*)d_in[0];
  const float* tarr = (const float*)d_in[1];
  const float* W1   = (const float*)d_in[2];
  const float* b1   = (const float*)d_in[3];
  const float* W2   = (const float*)d_in[4];
  const float* b2   = (const float*)d_in[5];
  float* dout = (float*)d_out;

  char* ws = (char*)d_ws;
  float* y32             = (float*)(ws);                          // 8 MB
  float* acc32           = (float*)(ws + (8u << 20));             // 8 MB
  unsigned short* tmp_bf = (unsigned short*)(ws + (16u << 20));   // 4 MB (NHWC)
  unsigned short* z_bf   = (unsigned short*)(ws + (20u << 20));   // 4 MB (NHWC)
  unsigned short* w1bf   = (unsigned short*)(ws + (24u << 20));   // 288 KB
  unsigned short* w2bf   = (unsigned short*)(ws + (24u << 20) + 294912);
  unsigned* bar          = (unsigned*)(ws + (24u << 20) + 655360);

  prep_weights<<<(2 * 147456 + 255) / 256, 256, 0, stream>>>(W1, W2, w1bf, w2bf);
  init_copy<<<(B_ * CHW_ + 255) / 256, 256, 0, stream>>>(y0, y32, dout);
  init_transpose<<<2048, 256, 0, stream>>>(y0, tmp_bf);
  hipMemsetAsync(bar, 0, 16 * 256, stream);

  unsigned short* w1p = w1bf; unsigned short* w2p = w2bf;
  const float* b1p = b1; const float* b2p = b2;
  unsigned short* tp = tmp_bf; unsigned short* zp = z_bf;
  float* yp = y32; float* ap = acc32; float* dp = dout;
  const float* tap = tarr; unsigned* bp = bar;
  void* kargs[] = {&w1p, &w2p, &b1p, &b2p, &tp, &zp, &yp, &ap, &dp, &tap, &bp};
  hipError_t rc = hipLaunchCooperativeKernel((void*)ode_persistent, dim3(NBLK), dim3(512),
                                             kargs, 0, stream);
  if (rc != hipSuccess) {
    // fallback: plain launch. 1 block/CU (LDS 37KB, VGPR<=256) -> co-resident.
    ode_persistent<<<NBLK, 512, 0, stream>>>(w1p, w2p, b1p, b2p, tp, zp, yp, ap, dp, tap, bp);
  }
}